// Round 5
// baseline (6608.176 us; speedup 1.0000x reference)
//
#include <hip/hip_runtime.h>
#include <stdint.h>

// ---------------------------------------------------------------------------
// BiRNNBowman: 4 masked LSTMs (p_fw,p_bw,h_fw,h_bw) + 4-layer MLP head.
// ALL float tensors are FLOAT32 (per the reference); lengths are int32.
// Compute path: bf16 MFMA with fp32 accumulation (threshold is 2% of ref max).
//
// One kernel (plain launch, 256 WGs = 1/CU) runs all 4 LSTMs:
//   - WG = (lstm l, row-group r: 64 batch rows, unit-group: 128 permuted cols)
//   - weights for the WG's 128 cols live in VGPRs; per step
//     z = [x_t|h_t]@[Wx;Wh] via 16x16x32 bf16 MFMA, A staged through
//     double-buffered LDS in 7 chunks.
//   - R4 change: h exchange is now TAG-SIGNALED DATA, no flag protocol.
//     Each h unit-pair is one u64 {tag=step : u32, data=2xbf16 : u32} stored
//     with a relaxed agent-scope atomic (single-copy atomic, no torn reads).
//     Consumers issue h loads early (overlapping x MFMA), then verify tags
//     at LDS-write time and re-poll only stale words (steady state: 0 spins).
//     This removes per step: producer store-drain barrier, release fetch_add
//     (MALL RMW), tid0 poll + broadcast barrier, end-of-step barrier -- the
//     ~4 serialized MALL hops that dominated (counters: MfmaUtil 7%, VALU 8%,
//     HBM 5.7% -- everything idle; 19.8us/step vs ~5us accountable).
//     Safety: parity double-buffer + the data-dependency chain (producer's
//     next same-parity write requires consuming h that the lagging consumer
//     produced AFTER its reads) -> one full step of slack, no overwrite race.
//     Guard-bounded spins (never hangs).
// ---------------------------------------------------------------------------

using u16 = unsigned short;
using u32 = uint32_t;
using u64 = unsigned long long;
using bf16x8 = __attribute__((ext_vector_type(8))) short;   // 8 bf16 (4 VGPRs)
using f32x4  = __attribute__((ext_vector_type(4))) float;   // MFMA acc

__device__ __forceinline__ float bf2f(u16 u) {
    union { u32 i; float f; } v; v.i = ((u32)u) << 16; return v.f;
}
__device__ __forceinline__ u16 f2bf(float f) {
    union { float f; u32 i; } v; v.f = f;
    u32 x = v.i;
    u32 r = (x + 0x7fffu + ((x >> 16) & 1u)) >> 16;   // RNE
    return (u16)r;
}
__device__ __forceinline__ float sigf(float x) {
    return __builtin_amdgcn_rcpf(1.0f + __builtin_amdgcn_exp2f(-1.442695041f * x));
}
__device__ __forceinline__ float tanhf_(float x) {
    return 1.0f - 2.0f * __builtin_amdgcn_rcpf(1.0f + __builtin_amdgcn_exp2f(2.885390082f * x));
}

// ---------------------------------------------------------------------------
// Transpose + f32->bf16 (+ optional gate/unit permutation):
// in f32 [K][N] -> out bf16 [N'][Kpad], out[P(o)][k] = in[k][o], zero-pad k>=K.
// perm=1: o = gate*512 + unit ; P = ug*128 + wq*32 + (gate>>1)*16 + c
//   with unit = ug*32 + wq*8 + u8 ; c = u8 + ((gate&1)<<3)
// ---------------------------------------------------------------------------
__global__ void birnn_tr(const float* __restrict__ in, u16* __restrict__ out,
                         int K, int N, int Kpad, int perm)
{
    __shared__ u16 t[64][65];
    const int k0 = blockIdx.x * 64, o0 = blockIdx.y * 64;
    const int tid = threadIdx.x;
    const int j = tid & 63, rg = tid >> 6;
    for (int it = 0; it < 16; it++) {
        int kl = it * 4 + rg;
        int kk = k0 + kl;
        t[kl][j] = (kk < K) ? f2bf(in[(size_t)kk * N + o0 + j]) : (u16)0;
    }
    __syncthreads();
    const int ii = tid & 63, jg = tid >> 6;
    for (int it = 0; it < 16; it++) {
        int jj = it * 4 + jg;
        int o = o0 + jj;
        int P;
        if (perm) {
            int gate = o >> 9, rr = o & 511;
            int ug = rr >> 5, rr2 = rr & 31, wq = rr2 >> 3, u8 = rr2 & 7;
            int tt = gate >> 1, c = u8 + ((gate & 1) << 3);
            P = ug * 128 + wq * 32 + tt * 16 + c;
        } else {
            P = o;
        }
        if (k0 + ii < Kpad)
            out[(size_t)P * Kpad + k0 + ii] = t[ii][jj];
    }
}

// Permuted f32 biases for the 4 LSTMs.
__global__ void birnn_bias(const float* __restrict__ b0, const float* __restrict__ b1,
                           const float* __restrict__ b2, const float* __restrict__ b3,
                           float* __restrict__ bp)
{
    int o = blockIdx.x * 256 + threadIdx.x;
    int l = blockIdx.y;
    const float* bs = (l == 0) ? b0 : (l == 1) ? b1 : (l == 2) ? b2 : b3;
    int gate = o >> 9, rr = o & 511;
    int ug = rr >> 5, rr2 = rr & 31, wq = rr2 >> 3, u8 = rr2 & 7;
    int tt = gate >> 1, c = u8 + ((gate & 1) << 3);
    int P = ug * 128 + wq * 32 + tt * 16 + c;
    bp[l * 2048 + P] = bs[o];
}

// ---------------------------------------------------------------------------
struct RnnP {
    const float* prem; const float* hyp;
    const int* plen;   const int* hlen;
    const u16* Whp;    const u16* Wxp;    const float* bp;
    u64* hbuf;         u16* xcat;
};

// f32 loads, RNE-pack to bf16 pairs
#define LOADX(ci, guarded)                                                        \
    do {                                                                          \
        size_t base_ = (size_t)grow * 76800 + (size_t)t_cur * 300                 \
                     + (ci) * 128 + seg * 32;                                     \
        const float4* p_ = (const float4*)(xsrc + base_);                         \
        _Pragma("unroll")                                                         \
        for (int j_ = 0; j_ < 8; j_++) {                                          \
            int d_ = (ci) * 128 + seg * 32 + j_ * 4;                              \
            if (!(guarded) || d_ < 300) {                                         \
                float4 f_ = p_[j_];                                               \
                sv[j_] = make_uint2((u32)f2bf(f_.x) | ((u32)f2bf(f_.y) << 16),    \
                                    (u32)f2bf(f_.z) | ((u32)f2bf(f_.w) << 16));   \
            } else sv[j_] = make_uint2(0u, 0u);                                   \
        }                                                                         \
    } while (0)

// Issue 16 tagged-u64 h loads for chunk ci (units ci*128+seg*32 .. +31).
// Relaxed agent-scope atomics: single-copy atomic {tag,data} words.
#define LOADH(ci)                                                                 \
    do {                                                                          \
        const u64* p_ = hread + (size_t)grow * 256 + (ci) * 64 + seg * 16;        \
        _Pragma("unroll")                                                         \
        for (int j_ = 0; j_ < 16; j_++)                                           \
            hv[j_] = __hip_atomic_load(p_ + j_, __ATOMIC_RELAXED,                 \
                                       __HIP_MEMORY_SCOPE_AGENT);                 \
    } while (0)

#define WRLDS(pb)                                                                 \
    do {                                                                          \
        int4* dst_ = (int4*)&Asmem[(pb)][row][seg * 32];                          \
        _Pragma("unroll")                                                         \
        for (int j_ = 0; j_ < 4; j_++)                                            \
            dst_[j_] = make_int4((int)sv[2*j_].x, (int)sv[2*j_].y,                \
                                 (int)sv[2*j_+1].x, (int)sv[2*j_+1].y);           \
    } while (0)

// Verify tags of hv (re-poll stale words; steady state 0 iterations),
// then write the data halves to LDS.
#define WRLDSH(pb, ci)                                                            \
    do {                                                                          \
        const u64* p_ = hread + (size_t)grow * 256 + (ci) * 64 + seg * 16;        \
        _Pragma("unroll")                                                         \
        for (int j_ = 0; j_ < 16; j_++) {                                         \
            int g_ = 0;                                                           \
            while ((u32)(hv[j_] >> 32) != (u32)s && ++g_ < (1 << 18))             \
                hv[j_] = __hip_atomic_load(p_ + j_, __ATOMIC_RELAXED,             \
                                           __HIP_MEMORY_SCOPE_AGENT);            \
        }                                                                         \
        int4* dst_ = (int4*)&Asmem[(pb)][row][seg * 32];                          \
        _Pragma("unroll")                                                         \
        for (int j_ = 0; j_ < 4; j_++)                                            \
            dst_[j_] = make_int4((int)(u32)hv[4*j_],   (int)(u32)hv[4*j_+1],      \
                                 (int)(u32)hv[4*j_+2], (int)(u32)hv[4*j_+3]);     \
    } while (0)

#define MCHUNK(pb, fb, nk)                                                        \
    do {                                                                          \
        _Pragma("unroll")                                                         \
        for (int kk_ = 0; kk_ < (nk); kk_++) {                                    \
            bf16x8 af_[4];                                                        \
            _Pragma("unroll")                                                     \
            for (int m_ = 0; m_ < 4; m_++)                                        \
                af_[m_] = *(const bf16x8*)&Asmem[(pb)][m_ * 16 + c0]              \
                                                [kk_ * 32 + quad * 8];            \
            _Pragma("unroll")                                                     \
            for (int m_ = 0; m_ < 4; m_++) {                                      \
                acc[m_][0] = __builtin_amdgcn_mfma_f32_16x16x32_bf16(             \
                    af_[m_], bfr[(fb) + kk_][0], acc[m_][0], 0, 0, 0);            \
                acc[m_][1] = __builtin_amdgcn_mfma_f32_16x16x32_bf16(             \
                    af_[m_], bfr[(fb) + kk_][1], acc[m_][1], 0, 0, 0);            \
            }                                                                     \
        }                                                                         \
    } while (0)

__global__ __launch_bounds__(256, 1) void birnn_rnn(RnnP P_)
{
    const int tid  = threadIdx.x;
    const int bid  = blockIdx.x;
    const int g    = bid & 15;       // group id (l*4 + r); same-XCD for all ugrps
    const int ugrp = bid >> 4;       // 0..15 unit group
    const int l = g >> 2, r = g & 3;
    const int wq = tid >> 6, L = tid & 63, c0 = L & 15, quad = L >> 4;
    const int row = tid >> 2, seg = tid & 3;   // staging role
    const int grow = r * 64 + row;

    const float* xsrc = (l < 2) ? P_.prem : P_.hyp;
    const int* lens = (l < 2) ? P_.plen : P_.hlen;
    u64* hl = P_.hbuf + (size_t)l * 131072;     // 2 parity buffers [256][256] u64

    __shared__ u16 Asmem[2][64][136];           // double-buffered A chunk

    // ---- register-resident B fragments from pre-permuted bf16 Wxp/Whp ----
    bf16x8 bfr[26][2];
    {
        const u16* WxpL = P_.Wxp + (size_t)l * 2048 * 320;
        const u16* WhpL = P_.Whp + (size_t)l * 2048 * 512;
#pragma unroll
        for (int t = 0; t < 2; t++) {
            int P = ugrp * 128 + wq * 32 + t * 16 + c0;
#pragma unroll
            for (int ks = 0; ks < 10; ks++)
                bfr[ks][t] = *(const bf16x8*)(WxpL + (size_t)P * 320 + ks * 32 + quad * 8);
#pragma unroll
            for (int ks = 0; ks < 16; ks++)
                bfr[10 + ks][t] = *(const bf16x8*)(WhpL + (size_t)P * 512 + ks * 32 + quad * 8);
        }
    }
    const float bias0 = P_.bp[l * 2048 + ugrp * 128 + wq * 32 + c0];
    const float bias1 = P_.bp[l * 2048 + ugrp * 128 + wq * 32 + 16 + c0];

    const int rsel0 = (c0 < 8) ? 0 : 2;
    const int ugl = ugrp * 32 + wq * 8 + (c0 & 7);

    int len8[8];
#pragma unroll
    for (int m = 0; m < 4; m++)
#pragma unroll
        for (int rr = 0; rr < 2; rr++)
            len8[m * 2 + rr] = lens[r * 64 + m * 16 + quad * 4 + rsel0 + rr];

    float c8[8] = {0, 0, 0, 0, 0, 0, 0, 0};
    float h8[8] = {0, 0, 0, 0, 0, 0, 0, 0};

    int p = 0;
#pragma unroll 1
    for (int s = 0; s < 256; s++) {
        const int t_cur = (l & 1) ? (255 - s) : s;
        const u64* hread = hl + (s & 1) * 65536;
        u64* hwrite = hl + ((s + 1) & 1) * 65536;

        f32x4 acc[4][2];
#pragma unroll
        for (int m = 0; m < 4; m++) {
            f32x4 z = {0.f, 0.f, 0.f, 0.f};
            acc[m][0] = z; acc[m][1] = z;
        }
        uint2 sv[8];
        u64 hv[16];

        // ---- x chunks ----
        LOADX(0, 0); WRLDS(p); __syncthreads();
        LOADX(1, 0);
        MCHUNK(p, 0, 4);                       // chunk x0
        WRLDS(p ^ 1); __syncthreads();
        LOADX(2, 1);
        MCHUNK(p ^ 1, 4, 4);                   // chunk x1
        WRLDS(p); __syncthreads();
        if (s > 0) LOADH(0);                   // issue h reads, overlap x2 MFMA
        MCHUNK(p, 8, 2);                       // chunk x2 (K=64 valid)
        if (s > 0) {
            WRLDSH(p ^ 1, 0); __syncthreads(); // verify tags + h0 into LDS
            LOADH(1);
            MCHUNK(p ^ 1, 10, 4);              // h0
            WRLDSH(p, 1); __syncthreads();
            LOADH(2);
            MCHUNK(p, 14, 4);                  // h1
            WRLDSH(p ^ 1, 2); __syncthreads();
            LOADH(3);
            MCHUNK(p ^ 1, 18, 4);              // h2
            WRLDSH(p, 3); __syncthreads();
            MCHUNK(p, 22, 4);                  // h3
        }

        // ---- epilogue: gates, state update, masked h/c, tagged h store ----
#pragma unroll
        for (int m = 0; m < 4; m++) {
            float z0[4], z1[4], t0v[4], t1v[4];
#pragma unroll
            for (int reg = 0; reg < 4; reg++) {
                z0[reg] = acc[m][0][reg] + bias0;
                z1[reg] = acc[m][1][reg] + bias1;
            }
#pragma unroll
            for (int reg = 0; reg < 4; reg++) {
                t0v[reg] = __shfl_xor(z0[reg], 8, 64);
                t1v[reg] = __shfl_xor(z1[reg], 8, 64);
            }
#pragma unroll
            for (int rr = 0; rr < 2; rr++) {
                const int reg = rsel0 + rr, idx = m * 2 + rr;
                const bool lo = (c0 < 8);
                float iv = lo ? z0[reg]  : t0v[reg];
                float jv = lo ? t0v[reg] : z0[reg];
                float fv = lo ? z1[reg]  : t1v[reg];
                float ov = lo ? t1v[reg] : z1[reg];
                float nc = c8[idx] * sigf(fv + 1.0f) + sigf(iv) * tanhf_(jv);
                float nh = tanhf_(nc) * sigf(ov);
                const bool mk = (t_cur < len8[idx]);
                c8[idx] = mk ? nc : c8[idx];
                h8[idx] = mk ? nh : h8[idx];
                const int b = r * 64 + m * 16 + quad * 4 + reg;
                u32 hb = (u32)f2bf(h8[idx]);
                u32 pr = __shfl_xor(hb, 1, 64);
                if ((c0 & 1) == 0) {
                    u64 pk = ((u64)(u32)(s + 1) << 32)
                           | (u64)(hb | (pr << 16));
                    __hip_atomic_store(hwrite + (size_t)b * 256 + (ugl >> 1), pk,
                                       __ATOMIC_RELAXED, __HIP_MEMORY_SCOPE_AGENT);
                }
            }
        }
        p ^= 1;    // no end-of-step barrier: tag-signaled data needs no drain
    }

    // ---- final cell states -> xcat [256][2048] = [c_pfw|c_pbw|c_hfw|c_hbw] ----
#pragma unroll
    for (int m = 0; m < 4; m++)
#pragma unroll
        for (int rr = 0; rr < 2; rr++) {
            const int reg = rsel0 + rr, idx = m * 2 + rr;
            const int b = r * 64 + m * 16 + quad * 4 + reg;
            P_.xcat[(size_t)b * 2048 + l * 512 + ugl] = f2bf(c8[idx]);
        }
}

// ---------------------------------------------------------------------------
// MLP GEMM: out[M=256][N] = act(A_bf16[256][K] @ W_f32[K][N] + bias_f32).
// B-fragments gathered strided from original f32 W (cache-resident, 2 GFLOP).
// ---------------------------------------------------------------------------
__global__ __launch_bounds__(256) void birnn_mlp(const u16* __restrict__ A,
                                                 const float* __restrict__ W,
                                                 const float* __restrict__ bias,
                                                 u16* __restrict__ out,
                                                 int N, int K, int act)
{
    const int tid = threadIdx.x, wq = tid >> 6, L = tid & 63;
    const int c0 = L & 15, quad = L >> 4;
    const int bm = blockIdx.x * 64;
    const int col = blockIdx.y * 64 + wq * 16 + c0;
    f32x4 acc[4];
#pragma unroll
    for (int m = 0; m < 4; m++) { f32x4 z = {0.f, 0.f, 0.f, 0.f}; acc[m] = z; }
    const int ksn = K >> 5;
    for (int ks = 0; ks < ksn; ks++) {
        bf16x8 bfrag;
#pragma unroll
        for (int j = 0; j < 8; j++)
            bfrag[j] = (short)f2bf(W[(size_t)(ks * 32 + quad * 8 + j) * N + col]);
#pragma unroll
        for (int m = 0; m < 4; m++) {
            bf16x8 afrag = *(const bf16x8*)(A + (size_t)(bm + m * 16 + c0) * K
                                            + ks * 32 + quad * 8);
            acc[m] = __builtin_amdgcn_mfma_f32_16x16x32_bf16(afrag, bfrag, acc[m], 0, 0, 0);
        }
    }
    const float bs = bias[col];
#pragma unroll
    for (int m = 0; m < 4; m++)
#pragma unroll
        for (int reg = 0; reg < 4; reg++) {
            float v = acc[m][reg] + bs;
            if (act) v = tanhf_(v);
            out[(size_t)(bm + m * 16 + quad * 4 + reg) * N + col] = f2bf(v);
        }
}

// Final layer: logits_f32[256][3] = h3_bf16[256][1024] @ W4_f32[1024][3] + b4.
__global__ void birnn_out(const u16* __restrict__ h3, const float* __restrict__ W4,
                          const float* __restrict__ b4, float* __restrict__ out)
{
    const int b = blockIdx.x;
    const int w = threadIdx.x >> 6, lane = threadIdx.x & 63;
    float s = 0.f;
    for (int it = 0; it < 16; it++) {
        int k = it * 64 + lane;
        s += bf2f(h3[b * 1024 + k]) * W4[k * 3 + w];
    }
#pragma unroll
    for (int off = 32; off > 0; off >>= 1) s += __shfl_down(s, off, 64);
    if (lane == 0) out[b * 3 + w] = s + b4[w];
}

// ---------------------------------------------------------------------------
extern "C" void kernel_launch(void* const* d_in, const int* in_sizes, int n_in,
                              void* d_out, int out_size, void* d_ws, size_t ws_size,
                              hipStream_t stream)
{
    const float* prem = (const float*)d_in[0];
    const float* hyp  = (const float*)d_in[1];
    const int* plen = (const int*)d_in[2];
    const int* hlen = (const int*)d_in[3];
    const float* Wx[4] = {(const float*)d_in[4],  (const float*)d_in[7],
                          (const float*)d_in[10], (const float*)d_in[13]};
    const float* Wh[4] = {(const float*)d_in[5],  (const float*)d_in[8],
                          (const float*)d_in[11], (const float*)d_in[14]};
    const float* bb[4] = {(const float*)d_in[6],  (const float*)d_in[9],
                          (const float*)d_in[12], (const float*)d_in[15]};
    const float* W1 = (const float*)d_in[16]; const float* b1 = (const float*)d_in[17];
    const float* W2 = (const float*)d_in[18]; const float* b2 = (const float*)d_in[19];
    const float* W3 = (const float*)d_in[20]; const float* b3 = (const float*)d_in[21];
    const float* W4 = (const float*)d_in[22]; const float* b4 = (const float*)d_in[23];

    // workspace carve (19,955,712 B total)
    char* w = (char*)d_ws;
    u64*  hbuf = (u64*)(w + 0);            // 4 x 2 x [256][256] u64 = 4,194,304
    u16*  xcat = (u16*)(w + 4194304);      // [256][2048] bf16 = 1,048,576
    u16*  h1   = (u16*)(w + 5242880);      // [256][1024] bf16 =   524,288
    u16*  h2   = (u16*)(w + 5767168);      // [256][1024] bf16 =   524,288
    u16*  Whp  = (u16*)(w + 6291456);      // 4 x [2048][512] bf16 = 8,388,608
    u16*  Wxp  = (u16*)(w + 14680064);     // 4 x [2048][320] bf16 = 5,242,880
    float* bp  = (float*)(w + 19922944);   // 4 x 2048 f32 = 32,768
    u16*  h3   = xcat;                     // xcat dead after MLP layer 1: reuse

    if (ws_size < 19955712) return;        // too-small ws -> zero output
                                           // (finite signature, diagnosable)

    hipMemsetAsync(hbuf, 0, 4194304, stream);   // tags = 0: never matches s>=1
    hipMemsetAsync(xcat, 0, 1048576, stream);

    for (int l = 0; l < 4; l++) {
        birnn_tr<<<dim3(8, 32), 256, 0, stream>>>(Wh[l], Whp + (size_t)l * 2048 * 512,
                                                  512, 2048, 512, 1);
        birnn_tr<<<dim3(5, 32), 256, 0, stream>>>(Wx[l], Wxp + (size_t)l * 2048 * 320,
                                                  300, 2048, 320, 1);
    }
    birnn_bias<<<dim3(8, 4), 256, 0, stream>>>(bb[0], bb[1], bb[2], bb[3], bp);

    RnnP pp{prem, hyp, plen, hlen, Whp, Wxp, bp, hbuf, xcat};
    birnn_rnn<<<dim3(256), dim3(256), 0, stream>>>(pp);

    birnn_mlp<<<dim3(4, 16), 256, 0, stream>>>(xcat, W1, b1, h1, 1024, 2048, 1);
    birnn_mlp<<<dim3(4, 16), 256, 0, stream>>>(h1,   W2, b2, h2, 1024, 1024, 1);
    birnn_mlp<<<dim3(4, 16), 256, 0, stream>>>(h2,   W3, b3, h3, 1024, 1024, 1);
    birnn_out<<<dim3(256), 192, 0, stream>>>(h3, W4, b4, (float*)d_out);
}

// Round 6
// 5054.074 us; speedup vs baseline: 1.3075x; 1.3075x over previous
//
#include <hip/hip_runtime.h>
#include <stdint.h>

// ---------------------------------------------------------------------------
// BiRNNBowman: 4 masked LSTMs (p_fw,p_bw,h_fw,h_bw) + 4-layer MLP head.
// ALL float tensors are FLOAT32 (per the reference); lengths are int32.
// Compute path: bf16 MFMA with fp32 accumulation (threshold is 2% of ref max).
//
// One kernel (plain launch, 256 WGs = 1/CU) runs all 4 LSTMs:
//   - WG = (lstm l, row-group r: 64 batch rows, unit-group: 128 permuted cols)
//   - weights for the WG's 128 cols live in VGPRs; per step
//     z = [x_t|h_t]@[Wx;Wh] via 16x16x32 bf16 MFMA, A staged through
//     double-buffered LDS in 7 chunks.
//   - h exchange: TAG-SIGNALED DATA (R4), now through the XCD's L2 (R5).
//     Each h unit-pair is one u64 {tag=step : u32, data=2xbf16 : u32}.
//     The 16 WGs of a group are co-resident on ONE XCD (bid&15=g =>
//     bid%8=g%8 under round-robin dispatch), so their shared L2 is the
//     coherence point. Stores/loads use inline-asm sc0 (bypass L1, hit L2):
//     R5 counter evidence: agent-scope (sc1) atomics forced every h access
//     + every spin re-poll to the MALL (FETCH_SIZE 333->462MB, ~250 MALL
//     re-polls/WG-step) and regressed 5.1->6.4ms. sc0 keeps the exchange
//     on-XCD: one fetch warms L2 for all 16 consumers, re-polls are L2 hits.
//     8B-aligned dwordx2 is single-copy atomic in L2 (no torn tag/data).
//     Safety: parity double-buffer + causal chain (producer's next
//     same-parity write happens only after consuming h the lagging consumer
//     produced AFTER its reads) -> one step slack, no overwrite race.
//     Guard-bounded spins (never hangs). If dispatch were NOT round-robin,
//     tags never match -> guard exits -> validation fails (diagnosable).
// ---------------------------------------------------------------------------

using u16 = unsigned short;
using u32 = uint32_t;
using u64 = unsigned long long;
using bf16x8 = __attribute__((ext_vector_type(8))) short;   // 8 bf16 (4 VGPRs)
using f32x4  = __attribute__((ext_vector_type(4))) float;   // MFMA acc

__device__ __forceinline__ float bf2f(u16 u) {
    union { u32 i; float f; } v; v.i = ((u32)u) << 16; return v.f;
}
__device__ __forceinline__ u16 f2bf(float f) {
    union { float f; u32 i; } v; v.f = f;
    u32 x = v.i;
    u32 r = (x + 0x7fffu + ((x >> 16) & 1u)) >> 16;   // RNE
    return (u16)r;
}
__device__ __forceinline__ float sigf(float x) {
    return __builtin_amdgcn_rcpf(1.0f + __builtin_amdgcn_exp2f(-1.442695041f * x));
}
__device__ __forceinline__ float tanhf_(float x) {
    return 1.0f - 2.0f * __builtin_amdgcn_rcpf(1.0f + __builtin_amdgcn_exp2f(2.885390082f * x));
}

// ---- sc0 (L1-bypass, L2-coherent) 8B access helpers ----
__device__ __forceinline__ void ldh_issue(const u64* p, u64& r) {
    // issue WITHOUT waitcnt: caller pipelines 16 of these, then HWAIT().
    asm volatile("global_load_dwordx2 %0, %1, off sc0" : "=v"(r) : "v"(p));
}
__device__ __forceinline__ u64 ldh_wait(const u64* p) {
    u64 r;
    asm volatile("global_load_dwordx2 %0, %1, off sc0\n\t"
                 "s_waitcnt vmcnt(0)"
                 : "=v"(r) : "v"(p) : "memory");
    return r;
}
__device__ __forceinline__ void sth_sc0(u64* p, u64 v) {
    asm volatile("global_store_dwordx2 %0, %1, off sc0" :: "v"(p), "v"(v) : "memory");
}
#define HWAIT()                                                                   \
    do {                                                                          \
        asm volatile("s_waitcnt vmcnt(0)" ::: "memory");                          \
        __builtin_amdgcn_sched_barrier(0);                                        \
    } while (0)

// ---------------------------------------------------------------------------
// Transpose + f32->bf16 (+ optional gate/unit permutation):
// in f32 [K][N] -> out bf16 [N'][Kpad], out[P(o)][k] = in[k][o], zero-pad k>=K.
// perm=1: o = gate*512 + unit ; P = ug*128 + wq*32 + (gate>>1)*16 + c
//   with unit = ug*32 + wq*8 + u8 ; c = u8 + ((gate&1)<<3)
// ---------------------------------------------------------------------------
__global__ void birnn_tr(const float* __restrict__ in, u16* __restrict__ out,
                         int K, int N, int Kpad, int perm)
{
    __shared__ u16 t[64][65];
    const int k0 = blockIdx.x * 64, o0 = blockIdx.y * 64;
    const int tid = threadIdx.x;
    const int j = tid & 63, rg = tid >> 6;
    for (int it = 0; it < 16; it++) {
        int kl = it * 4 + rg;
        int kk = k0 + kl;
        t[kl][j] = (kk < K) ? f2bf(in[(size_t)kk * N + o0 + j]) : (u16)0;
    }
    __syncthreads();
    const int ii = tid & 63, jg = tid >> 6;
    for (int it = 0; it < 16; it++) {
        int jj = it * 4 + jg;
        int o = o0 + jj;
        int P;
        if (perm) {
            int gate = o >> 9, rr = o & 511;
            int ug = rr >> 5, rr2 = rr & 31, wq = rr2 >> 3, u8 = rr2 & 7;
            int tt = gate >> 1, c = u8 + ((gate & 1) << 3);
            P = ug * 128 + wq * 32 + tt * 16 + c;
        } else {
            P = o;
        }
        if (k0 + ii < Kpad)
            out[(size_t)P * Kpad + k0 + ii] = t[ii][jj];
    }
}

// Permuted f32 biases for the 4 LSTMs.
__global__ void birnn_bias(const float* __restrict__ b0, const float* __restrict__ b1,
                           const float* __restrict__ b2, const float* __restrict__ b3,
                           float* __restrict__ bp)
{
    int o = blockIdx.x * 256 + threadIdx.x;
    int l = blockIdx.y;
    const float* bs = (l == 0) ? b0 : (l == 1) ? b1 : (l == 2) ? b2 : b3;
    int gate = o >> 9, rr = o & 511;
    int ug = rr >> 5, rr2 = rr & 31, wq = rr2 >> 3, u8 = rr2 & 7;
    int tt = gate >> 1, c = u8 + ((gate & 1) << 3);
    int P = ug * 128 + wq * 32 + tt * 16 + c;
    bp[l * 2048 + P] = bs[o];
}

// ---------------------------------------------------------------------------
struct RnnP {
    const float* prem; const float* hyp;
    const int* plen;   const int* hlen;
    const u16* Whp;    const u16* Wxp;    const float* bp;
    u64* hbuf;         u16* xcat;
};

// f32 loads, RNE-pack to bf16 pairs
#define LOADX(ci, guarded)                                                        \
    do {                                                                          \
        size_t base_ = (size_t)grow * 76800 + (size_t)t_cur * 300                 \
                     + (ci) * 128 + seg * 32;                                     \
        const float4* p_ = (const float4*)(xsrc + base_);                         \
        _Pragma("unroll")                                                         \
        for (int j_ = 0; j_ < 8; j_++) {                                          \
            int d_ = (ci) * 128 + seg * 32 + j_ * 4;                              \
            if (!(guarded) || d_ < 300) {                                         \
                float4 f_ = p_[j_];                                               \
                sv[j_] = make_uint2((u32)f2bf(f_.x) | ((u32)f2bf(f_.y) << 16),    \
                                    (u32)f2bf(f_.z) | ((u32)f2bf(f_.w) << 16));   \
            } else sv[j_] = make_uint2(0u, 0u);                                   \
        }                                                                         \
    } while (0)

// Issue 16 tagged-u64 h loads for chunk ci (units ci*128+seg*32 .. +31).
// sc0: pipelined L2 reads, no waitcnt here (HWAIT in WRLDSH).
#define LOADH(ci)                                                                 \
    do {                                                                          \
        const u64* p_ = hread + (size_t)grow * 256 + (ci) * 64 + seg * 16;        \
        _Pragma("unroll")                                                         \
        for (int j_ = 0; j_ < 16; j_++)                                           \
            ldh_issue(p_ + j_, hv[j_]);                                           \
    } while (0)

#define WRLDS(pb)                                                                 \
    do {                                                                          \
        int4* dst_ = (int4*)&Asmem[(pb)][row][seg * 32];                          \
        _Pragma("unroll")                                                         \
        for (int j_ = 0; j_ < 4; j_++)                                            \
            dst_[j_] = make_int4((int)sv[2*j_].x, (int)sv[2*j_].y,                \
                                 (int)sv[2*j_+1].x, (int)sv[2*j_+1].y);           \
    } while (0)

// Wait for the issued h loads, verify tags (re-poll stale words via L2;
// steady state 0 iterations), then write the data halves to LDS.
#define WRLDSH(pb, ci)                                                            \
    do {                                                                          \
        HWAIT();                                                                  \
        const u64* p_ = hread + (size_t)grow * 256 + (ci) * 64 + seg * 16;        \
        _Pragma("unroll")                                                         \
        for (int j_ = 0; j_ < 16; j_++) {                                         \
            int g_ = 0;                                                           \
            while ((u32)(hv[j_] >> 32) != (u32)s && ++g_ < (1 << 18))             \
                hv[j_] = ldh_wait(p_ + j_);                                       \
        }                                                                         \
        int4* dst_ = (int4*)&Asmem[(pb)][row][seg * 32];                          \
        _Pragma("unroll")                                                         \
        for (int j_ = 0; j_ < 4; j_++)                                            \
            dst_[j_] = make_int4((int)(u32)hv[4*j_],   (int)(u32)hv[4*j_+1],      \
                                 (int)(u32)hv[4*j_+2], (int)(u32)hv[4*j_+3]);     \
    } while (0)

#define MCHUNK(pb, fb, nk)                                                        \
    do {                                                                          \
        _Pragma("unroll")                                                         \
        for (int kk_ = 0; kk_ < (nk); kk_++) {                                    \
            bf16x8 af_[4];                                                        \
            _Pragma("unroll")                                                     \
            for (int m_ = 0; m_ < 4; m_++)                                        \
                af_[m_] = *(const bf16x8*)&Asmem[(pb)][m_ * 16 + c0]              \
                                                [kk_ * 32 + quad * 8];            \
            _Pragma("unroll")                                                     \
            for (int m_ = 0; m_ < 4; m_++) {                                      \
                acc[m_][0] = __builtin_amdgcn_mfma_f32_16x16x32_bf16(             \
                    af_[m_], bfr[(fb) + kk_][0], acc[m_][0], 0, 0, 0);            \
                acc[m_][1] = __builtin_amdgcn_mfma_f32_16x16x32_bf16(             \
                    af_[m_], bfr[(fb) + kk_][1], acc[m_][1], 0, 0, 0);            \
            }                                                                     \
        }                                                                         \
    } while (0)

__global__ __launch_bounds__(256, 1) void birnn_rnn(RnnP P_)
{
    const int tid  = threadIdx.x;
    const int bid  = blockIdx.x;
    const int g    = bid & 15;       // group id (l*4 + r); same-XCD for all ugrps
    const int ugrp = bid >> 4;       // 0..15 unit group
    const int l = g >> 2, r = g & 3;
    const int wq = tid >> 6, L = tid & 63, c0 = L & 15, quad = L >> 4;
    const int row = tid >> 2, seg = tid & 3;   // staging role
    const int grow = r * 64 + row;

    const float* xsrc = (l < 2) ? P_.prem : P_.hyp;
    const int* lens = (l < 2) ? P_.plen : P_.hlen;
    u64* hl = P_.hbuf + (size_t)l * 131072;     // 2 parity buffers [256][256] u64

    __shared__ u16 Asmem[2][64][136];           // double-buffered A chunk

    // ---- register-resident B fragments from pre-permuted bf16 Wxp/Whp ----
    bf16x8 bfr[26][2];
    {
        const u16* WxpL = P_.Wxp + (size_t)l * 2048 * 320;
        const u16* WhpL = P_.Whp + (size_t)l * 2048 * 512;
#pragma unroll
        for (int t = 0; t < 2; t++) {
            int P = ugrp * 128 + wq * 32 + t * 16 + c0;
#pragma unroll
            for (int ks = 0; ks < 10; ks++)
                bfr[ks][t] = *(const bf16x8*)(WxpL + (size_t)P * 320 + ks * 32 + quad * 8);
#pragma unroll
            for (int ks = 0; ks < 16; ks++)
                bfr[10 + ks][t] = *(const bf16x8*)(WhpL + (size_t)P * 512 + ks * 32 + quad * 8);
        }
    }
    const float bias0 = P_.bp[l * 2048 + ugrp * 128 + wq * 32 + c0];
    const float bias1 = P_.bp[l * 2048 + ugrp * 128 + wq * 32 + 16 + c0];

    const int rsel0 = (c0 < 8) ? 0 : 2;
    const int ugl = ugrp * 32 + wq * 8 + (c0 & 7);

    int len8[8];
#pragma unroll
    for (int m = 0; m < 4; m++)
#pragma unroll
        for (int rr = 0; rr < 2; rr++)
            len8[m * 2 + rr] = lens[r * 64 + m * 16 + quad * 4 + rsel0 + rr];

    float c8[8] = {0, 0, 0, 0, 0, 0, 0, 0};
    float h8[8] = {0, 0, 0, 0, 0, 0, 0, 0};

    int p = 0;
#pragma unroll 1
    for (int s = 0; s < 256; s++) {
        const int t_cur = (l & 1) ? (255 - s) : s;
        const u64* hread = hl + (s & 1) * 65536;
        u64* hwrite = hl + ((s + 1) & 1) * 65536;

        f32x4 acc[4][2];
#pragma unroll
        for (int m = 0; m < 4; m++) {
            f32x4 z = {0.f, 0.f, 0.f, 0.f};
            acc[m][0] = z; acc[m][1] = z;
        }
        uint2 sv[8];
        u64 hv[16];

        // ---- x chunks ----
        LOADX(0, 0); WRLDS(p); __syncthreads();
        LOADX(1, 0);
        MCHUNK(p, 0, 4);                       // chunk x0
        WRLDS(p ^ 1); __syncthreads();
        LOADX(2, 1);
        MCHUNK(p ^ 1, 4, 4);                   // chunk x1
        WRLDS(p); __syncthreads();
        if (s > 0) LOADH(0);                   // issue h reads, overlap x2 MFMA
        MCHUNK(p, 8, 2);                       // chunk x2 (K=64 valid)
        if (s > 0) {
            WRLDSH(p ^ 1, 0); __syncthreads(); // wait+verify tags + h0 into LDS
            LOADH(1);
            MCHUNK(p ^ 1, 10, 4);              // h0
            WRLDSH(p, 1); __syncthreads();
            LOADH(2);
            MCHUNK(p, 14, 4);                  // h1
            WRLDSH(p ^ 1, 2); __syncthreads();
            LOADH(3);
            MCHUNK(p ^ 1, 18, 4);              // h2
            WRLDSH(p, 3); __syncthreads();
            MCHUNK(p, 22, 4);                  // h3
        }

        // ---- epilogue: gates, state update, masked h/c, tagged h store ----
#pragma unroll
        for (int m = 0; m < 4; m++) {
            float z0[4], z1[4], t0v[4], t1v[4];
#pragma unroll
            for (int reg = 0; reg < 4; reg++) {
                z0[reg] = acc[m][0][reg] + bias0;
                z1[reg] = acc[m][1][reg] + bias1;
            }
#pragma unroll
            for (int reg = 0; reg < 4; reg++) {
                t0v[reg] = __shfl_xor(z0[reg], 8, 64);
                t1v[reg] = __shfl_xor(z1[reg], 8, 64);
            }
#pragma unroll
            for (int rr = 0; rr < 2; rr++) {
                const int reg = rsel0 + rr, idx = m * 2 + rr;
                const bool lo = (c0 < 8);
                float iv = lo ? z0[reg]  : t0v[reg];
                float jv = lo ? t0v[reg] : z0[reg];
                float fv = lo ? z1[reg]  : t1v[reg];
                float ov = lo ? t1v[reg] : z1[reg];
                float nc = c8[idx] * sigf(fv + 1.0f) + sigf(iv) * tanhf_(jv);
                float nh = tanhf_(nc) * sigf(ov);
                const bool mk = (t_cur < len8[idx]);
                c8[idx] = mk ? nc : c8[idx];
                h8[idx] = mk ? nh : h8[idx];
                const int b = r * 64 + m * 16 + quad * 4 + reg;
                u32 hb = (u32)f2bf(h8[idx]);
                u32 pr = __shfl_xor(hb, 1, 64);
                if ((c0 & 1) == 0) {
                    u64 pk = ((u64)(u32)(s + 1) << 32)
                           | (u64)(hb | (pr << 16));
                    sth_sc0(hwrite + (size_t)b * 256 + (ugl >> 1), pk);
                }
            }
        }
        p ^= 1;    // no end-of-step barrier: tag-signaled data needs no drain
    }

    // ---- final cell states -> xcat [256][2048] = [c_pfw|c_pbw|c_hfw|c_hbw] ----
#pragma unroll
    for (int m = 0; m < 4; m++)
#pragma unroll
        for (int rr = 0; rr < 2; rr++) {
            const int reg = rsel0 + rr, idx = m * 2 + rr;
            const int b = r * 64 + m * 16 + quad * 4 + reg;
            P_.xcat[(size_t)b * 2048 + l * 512 + ugl] = f2bf(c8[idx]);
        }
}

// ---------------------------------------------------------------------------
// MLP GEMM: out[M=256][N] = act(A_bf16[256][K] @ W_f32[K][N] + bias_f32).
// B-fragments gathered strided from original f32 W (cache-resident, 2 GFLOP).
// ---------------------------------------------------------------------------
__global__ __launch_bounds__(256) void birnn_mlp(const u16* __restrict__ A,
                                                 const float* __restrict__ W,
                                                 const float* __restrict__ bias,
                                                 u16* __restrict__ out,
                                                 int N, int K, int act)
{
    const int tid = threadIdx.x, wq = tid >> 6, L = tid & 63;
    const int c0 = L & 15, quad = L >> 4;
    const int bm = blockIdx.x * 64;
    const int col = blockIdx.y * 64 + wq * 16 + c0;
    f32x4 acc[4];
#pragma unroll
    for (int m = 0; m < 4; m++) { f32x4 z = {0.f, 0.f, 0.f, 0.f}; acc[m] = z; }
    const int ksn = K >> 5;
    for (int ks = 0; ks < ksn; ks++) {
        bf16x8 bfrag;
#pragma unroll
        for (int j = 0; j < 8; j++)
            bfrag[j] = (short)f2bf(W[(size_t)(ks * 32 + quad * 8 + j) * N + col]);
#pragma unroll
        for (int m = 0; m < 4; m++) {
            bf16x8 afrag = *(const bf16x8*)(A + (size_t)(bm + m * 16 + c0) * K
                                            + ks * 32 + quad * 8);
            acc[m] = __builtin_amdgcn_mfma_f32_16x16x32_bf16(afrag, bfrag, acc[m], 0, 0, 0);
        }
    }
    const float bs = bias[col];
#pragma unroll
    for (int m = 0; m < 4; m++)
#pragma unroll
        for (int reg = 0; reg < 4; reg++) {
            float v = acc[m][reg] + bs;
            if (act) v = tanhf_(v);
            out[(size_t)(bm + m * 16 + quad * 4 + reg) * N + col] = f2bf(v);
        }
}

// Final layer: logits_f32[256][3] = h3_bf16[256][1024] @ W4_f32[1024][3] + b4.
__global__ void birnn_out(const u16* __restrict__ h3, const float* __restrict__ W4,
                          const float* __restrict__ b4, float* __restrict__ out)
{
    const int b = blockIdx.x;
    const int w = threadIdx.x >> 6, lane = threadIdx.x & 63;
    float s = 0.f;
    for (int it = 0; it < 16; it++) {
        int k = it * 64 + lane;
        s += bf2f(h3[b * 1024 + k]) * W4[k * 3 + w];
    }
#pragma unroll
    for (int off = 32; off > 0; off >>= 1) s += __shfl_down(s, off, 64);
    if (lane == 0) out[b * 3 + w] = s + b4[w];
}

// ---------------------------------------------------------------------------
extern "C" void kernel_launch(void* const* d_in, const int* in_sizes, int n_in,
                              void* d_out, int out_size, void* d_ws, size_t ws_size,
                              hipStream_t stream)
{
    const float* prem = (const float*)d_in[0];
    const float* hyp  = (const float*)d_in[1];
    const int* plen = (const int*)d_in[2];
    const int* hlen = (const int*)d_in[3];
    const float* Wx[4] = {(const float*)d_in[4],  (const float*)d_in[7],
                          (const float*)d_in[10], (const float*)d_in[13]};
    const float* Wh[4] = {(const float*)d_in[5],  (const float*)d_in[8],
                          (const float*)d_in[11], (const float*)d_in[14]};
    const float* bb[4] = {(const float*)d_in[6],  (const float*)d_in[9],
                          (const float*)d_in[12], (const float*)d_in[15]};
    const float* W1 = (const float*)d_in[16]; const float* b1 = (const float*)d_in[17];
    const float* W2 = (const float*)d_in[18]; const float* b2 = (const float*)d_in[19];
    const float* W3 = (const float*)d_in[20]; const float* b3 = (const float*)d_in[21];
    const float* W4 = (const float*)d_in[22]; const float* b4 = (const float*)d_in[23];

    // workspace carve (19,955,712 B total)
    char* w = (char*)d_ws;
    u64*  hbuf = (u64*)(w + 0);            // 4 x 2 x [256][256] u64 = 4,194,304
    u16*  xcat = (u16*)(w + 4194304);      // [256][2048] bf16 = 1,048,576
    u16*  h1   = (u16*)(w + 5242880);      // [256][1024] bf16 =   524,288
    u16*  h2   = (u16*)(w + 5767168);      // [256][1024] bf16 =   524,288
    u16*  Whp  = (u16*)(w + 6291456);      // 4 x [2048][512] bf16 = 8,388,608
    u16*  Wxp  = (u16*)(w + 14680064);     // 4 x [2048][320] bf16 = 5,242,880
    float* bp  = (float*)(w + 19922944);   // 4 x 2048 f32 = 32,768
    u16*  h3   = xcat;                     // xcat dead after MLP layer 1: reuse

    if (ws_size < 19955712) return;        // too-small ws -> zero output
                                           // (finite signature, diagnosable)

    hipMemsetAsync(hbuf, 0, 4194304, stream);   // tags = 0: never matches s>=1
    hipMemsetAsync(xcat, 0, 1048576, stream);

    for (int l = 0; l < 4; l++) {
        birnn_tr<<<dim3(8, 32), 256, 0, stream>>>(Wh[l], Whp + (size_t)l * 2048 * 512,
                                                  512, 2048, 512, 1);
        birnn_tr<<<dim3(5, 32), 256, 0, stream>>>(Wx[l], Wxp + (size_t)l * 2048 * 320,
                                                  300, 2048, 320, 1);
    }
    birnn_bias<<<dim3(8, 4), 256, 0, stream>>>(bb[0], bb[1], bb[2], bb[3], bp);

    RnnP pp{prem, hyp, plen, hlen, Whp, Wxp, bp, hbuf, xcat};
    birnn_rnn<<<dim3(256), dim3(256), 0, stream>>>(pp);

    birnn_mlp<<<dim3(4, 16), 256, 0, stream>>>(xcat, W1, b1, h1, 1024, 2048, 1);
    birnn_mlp<<<dim3(4, 16), 256, 0, stream>>>(h1,   W2, b2, h2, 1024, 1024, 1);
    birnn_mlp<<<dim3(4, 16), 256, 0, stream>>>(h2,   W3, b3, h3, 1024, 1024, 1);
    birnn_out<<<dim3(256), 192, 0, stream>>>(h3, W4, b4, (float*)d_out);
}

// Round 7
// 3745.721 us; speedup vs baseline: 1.7642x; 1.3493x over previous
//
#include <hip/hip_runtime.h>
#include <stdint.h>

// ---------------------------------------------------------------------------
// BiRNNBowman: 4 masked LSTMs (p_fw,p_bw,h_fw,h_bw) + 4-layer MLP head.
// ALL float tensors are FLOAT32 (per the reference); lengths are int32.
// Compute path: bf16 MFMA with fp32 accumulation (threshold is 2% of ref max).
//
// One kernel (plain launch, 256 WGs) runs all 4 LSTMs:
//   - WG = (lstm l, row-group r: 64 batch rows, unit-group: 128 permuted cols)
//   - R6 change: 512 threads/WG (8 waves) instead of 256 (4 waves).
//     Counter evidence R3-R6: three exchange-protocol redesigns moved step
//     time only 19.8->18.7us while MfmaUtil 7.6%, VALUBusy 11%, HBM 0.6%,
//     Occupancy 12% (=1 wave/SIMD): pure latency-bound, zero hiding capacity.
//     Now: each wave owns ONE 16-col MFMA tile (weights 104 VGPR, fits
//     2 waves/SIMD under launch_bounds(512,2)) -> co-resident waves hide
//     each other's ds_read/global-load/VALU latencies.
//     A wave holds only gate pair (i,j) or (f,o) for its 8 units; the
//     epilogue swaps the missing pair through an 8KB LDS buffer (1 extra
//     barrier), and each wave of the pair processes half the rows.
//   - h exchange (UNCHANGED from R6, verified): tag-signaled u64
//     {tag=step, 2xbf16} via inline-asm sc0 (L1-bypass, XCD-L2 coherent);
//     the 16 WGs of a group are co-resident on one XCD (bid&15=g).
//     Guard-bounded spins (never hangs).
// ---------------------------------------------------------------------------

using u16 = unsigned short;
using u32 = uint32_t;
using u64 = unsigned long long;
using bf16x8 = __attribute__((ext_vector_type(8))) short;   // 8 bf16 (4 VGPRs)
using f32x4  = __attribute__((ext_vector_type(4))) float;   // MFMA acc

__device__ __forceinline__ float bf2f(u16 u) {
    union { u32 i; float f; } v; v.i = ((u32)u) << 16; return v.f;
}
__device__ __forceinline__ u16 f2bf(float f) {
    union { float f; u32 i; } v; v.f = f;
    u32 x = v.i;
    u32 r = (x + 0x7fffu + ((x >> 16) & 1u)) >> 16;   // RNE
    return (u16)r;
}
__device__ __forceinline__ float sigf(float x) {
    return __builtin_amdgcn_rcpf(1.0f + __builtin_amdgcn_exp2f(-1.442695041f * x));
}
__device__ __forceinline__ float tanhf_(float x) {
    return 1.0f - 2.0f * __builtin_amdgcn_rcpf(1.0f + __builtin_amdgcn_exp2f(2.885390082f * x));
}

// ---- sc0 (L1-bypass, L2-coherent) 8B access helpers ----
__device__ __forceinline__ void ldh_issue(const u64* p, u64& r) {
    asm volatile("global_load_dwordx2 %0, %1, off sc0" : "=v"(r) : "v"(p));
}
__device__ __forceinline__ u64 ldh_wait(const u64* p) {
    u64 r;
    asm volatile("global_load_dwordx2 %0, %1, off sc0\n\t"
                 "s_waitcnt vmcnt(0)"
                 : "=v"(r) : "v"(p) : "memory");
    return r;
}
__device__ __forceinline__ void sth_sc0(u64* p, u64 v) {
    asm volatile("global_store_dwordx2 %0, %1, off sc0" :: "v"(p), "v"(v) : "memory");
}
#define HWAIT()                                                                   \
    do {                                                                          \
        asm volatile("s_waitcnt vmcnt(0)" ::: "memory");                          \
        __builtin_amdgcn_sched_barrier(0);                                        \
    } while (0)

// ---------------------------------------------------------------------------
// Transpose + f32->bf16 (+ optional gate/unit permutation):
// in f32 [K][N] -> out bf16 [N'][Kpad], out[P(o)][k] = in[k][o], zero-pad k>=K.
// perm=1: o = gate*512 + unit ; P = ug*128 + wq*32 + (gate>>1)*16 + c
//   with unit = ug*32 + wq*8 + u8 ; c = u8 + ((gate&1)<<3)
// ---------------------------------------------------------------------------
__global__ void birnn_tr(const float* __restrict__ in, u16* __restrict__ out,
                         int K, int N, int Kpad, int perm)
{
    __shared__ u16 t[64][65];
    const int k0 = blockIdx.x * 64, o0 = blockIdx.y * 64;
    const int tid = threadIdx.x;
    const int j = tid & 63, rg = tid >> 6;
    for (int it = 0; it < 16; it++) {
        int kl = it * 4 + rg;
        int kk = k0 + kl;
        t[kl][j] = (kk < K) ? f2bf(in[(size_t)kk * N + o0 + j]) : (u16)0;
    }
    __syncthreads();
    const int ii = tid & 63, jg = tid >> 6;
    for (int it = 0; it < 16; it++) {
        int jj = it * 4 + jg;
        int o = o0 + jj;
        int P;
        if (perm) {
            int gate = o >> 9, rr = o & 511;
            int ug = rr >> 5, rr2 = rr & 31, wq = rr2 >> 3, u8 = rr2 & 7;
            int tt = gate >> 1, c = u8 + ((gate & 1) << 3);
            P = ug * 128 + wq * 32 + tt * 16 + c;
        } else {
            P = o;
        }
        if (k0 + ii < Kpad)
            out[(size_t)P * Kpad + k0 + ii] = t[ii][jj];
    }
}

// Permuted f32 biases for the 4 LSTMs.
__global__ void birnn_bias(const float* __restrict__ b0, const float* __restrict__ b1,
                           const float* __restrict__ b2, const float* __restrict__ b3,
                           float* __restrict__ bp)
{
    int o = blockIdx.x * 256 + threadIdx.x;
    int l = blockIdx.y;
    const float* bs = (l == 0) ? b0 : (l == 1) ? b1 : (l == 2) ? b2 : b3;
    int gate = o >> 9, rr = o & 511;
    int ug = rr >> 5, rr2 = rr & 31, wq = rr2 >> 3, u8 = rr2 & 7;
    int tt = gate >> 1, c = u8 + ((gate & 1) << 3);
    int P = ug * 128 + wq * 32 + tt * 16 + c;
    bp[l * 2048 + P] = bs[o];
}

// ---------------------------------------------------------------------------
struct RnnP {
    const float* prem; const float* hyp;
    const int* plen;   const int* hlen;
    const u16* Whp;    const u16* Wxp;    const float* bp;
    u64* hbuf;         u16* xcat;
};

// f32 loads, RNE-pack to bf16 pairs. 512 threads: row=tid>>3, seg=tid&7,
// 16 floats (4 float4) per thread per 128-dim chunk.
#define LOADX(ci, guarded)                                                        \
    do {                                                                          \
        size_t base_ = (size_t)grow * 76800 + (size_t)t_cur * 300                 \
                     + (ci) * 128 + seg * 16;                                     \
        const float4* p_ = (const float4*)(xsrc + base_);                         \
        _Pragma("unroll")                                                         \
        for (int j_ = 0; j_ < 4; j_++) {                                          \
            int d_ = (ci) * 128 + seg * 16 + j_ * 4;                              \
            if (!(guarded) || d_ + 3 < 300) {                                     \
                float4 f_ = p_[j_];                                               \
                sv[j_] = make_uint2((u32)f2bf(f_.x) | ((u32)f2bf(f_.y) << 16),    \
                                    (u32)f2bf(f_.z) | ((u32)f2bf(f_.w) << 16));   \
            } else sv[j_] = make_uint2(0u, 0u);                                   \
        }                                                                         \
    } while (0)

// Issue 8 tagged-u64 h loads for chunk ci (units ci*128 + seg*16 .. +15).
#define LOADH(ci)                                                                 \
    do {                                                                          \
        const u64* p_ = hread + (size_t)grow * 256 + (ci) * 64 + seg * 8;         \
        _Pragma("unroll")                                                         \
        for (int j_ = 0; j_ < 8; j_++)                                            \
            ldh_issue(p_ + j_, hv[j_]);                                           \
    } while (0)

#define WRLDS(pb)                                                                 \
    do {                                                                          \
        int4* dst_ = (int4*)&Asmem[(pb)][row][seg * 16];                          \
        dst_[0] = make_int4((int)sv[0].x, (int)sv[0].y, (int)sv[1].x, (int)sv[1].y); \
        dst_[1] = make_int4((int)sv[2].x, (int)sv[2].y, (int)sv[3].x, (int)sv[3].y); \
    } while (0)

// Wait issued h loads, verify tags (re-poll stale via L2; steady state 0),
// write data halves to LDS.
#define WRLDSH(pb, ci)                                                            \
    do {                                                                          \
        HWAIT();                                                                  \
        const u64* p_ = hread + (size_t)grow * 256 + (ci) * 64 + seg * 8;         \
        _Pragma("unroll")                                                         \
        for (int j_ = 0; j_ < 8; j_++) {                                          \
            int g_ = 0;                                                           \
            while ((u32)(hv[j_] >> 32) != (u32)s && ++g_ < (1 << 18))             \
                hv[j_] = ldh_wait(p_ + j_);                                       \
        }                                                                         \
        int4* dst_ = (int4*)&Asmem[(pb)][row][seg * 16];                          \
        dst_[0] = make_int4((int)(u32)hv[0], (int)(u32)hv[1],                     \
                            (int)(u32)hv[2], (int)(u32)hv[3]);                    \
        dst_[1] = make_int4((int)(u32)hv[4], (int)(u32)hv[5],                     \
                            (int)(u32)hv[6], (int)(u32)hv[7]);                    \
    } while (0)

// Single 16-col tile per wave.
#define MCHUNK(pb, fb, nk)                                                        \
    do {                                                                          \
        _Pragma("unroll")                                                         \
        for (int kk_ = 0; kk_ < (nk); kk_++) {                                    \
            bf16x8 af_[4];                                                        \
            _Pragma("unroll")                                                     \
            for (int m_ = 0; m_ < 4; m_++)                                        \
                af_[m_] = *(const bf16x8*)&Asmem[(pb)][m_ * 16 + c0]              \
                                                [kk_ * 32 + quad * 8];            \
            _Pragma("unroll")                                                     \
            for (int m_ = 0; m_ < 4; m_++)                                        \
                acc[m_] = __builtin_amdgcn_mfma_f32_16x16x32_bf16(                \
                    af_[m_], bfr[(fb) + kk_], acc[m_], 0, 0, 0);                  \
        }                                                                         \
    } while (0)

__global__ __launch_bounds__(512, 2) void birnn_rnn(RnnP P_)
{
    const int tid  = threadIdx.x;
    const int bid  = blockIdx.x;
    const int g    = bid & 15;       // group id (l*4 + r); same-XCD for all ugrps
    const int ugrp = bid >> 4;       // 0..15 unit group
    const int l = g >> 2, r = g & 3;
    const int wq = tid >> 6;         // wave 0..7
    const int L = tid & 63, c0 = L & 15, quad = L >> 4;
    const int p2 = wq >> 1;          // wave pair 0..3 (32-col block)
    const int role = wq & 1;         // 0: gates i,j (tt=0); 1: gates f,o (tt=1)
    const int row = tid >> 3, seg = tid & 7;   // staging role (512 threads)
    const int grow = r * 64 + row;

    const float* xsrc = (l < 2) ? P_.prem : P_.hyp;
    const int* lens = (l < 2) ? P_.plen : P_.hlen;
    u64* hl = P_.hbuf + (size_t)l * 131072;     // 2 parity buffers [256][256] u64

    __shared__ u16 Asmem[2][64][136];           // double-buffered A chunk
    __shared__ float2 exch0[4][2][2][64];       // role0 -> role1: (i,j) for m=2+mm
    __shared__ float2 exch1[4][2][2][64];       // role1 -> role0: (f,o) for m=mm

    // ---- register-resident B fragments (ONE 16-col tile per wave) ----
    bf16x8 bfr[26];
    {
        const u16* WxpL = P_.Wxp + (size_t)l * 2048 * 320;
        const u16* WhpL = P_.Whp + (size_t)l * 2048 * 512;
        const int P = ugrp * 128 + p2 * 32 + role * 16 + c0;
#pragma unroll
        for (int ks = 0; ks < 10; ks++)
            bfr[ks] = *(const bf16x8*)(WxpL + (size_t)P * 320 + ks * 32 + quad * 8);
#pragma unroll
        for (int ks = 0; ks < 16; ks++)
            bfr[10 + ks] = *(const bf16x8*)(WhpL + (size_t)P * 512 + ks * 32 + quad * 8);
    }
    const float biasw = P_.bp[l * 2048 + ugrp * 128 + p2 * 32 + role * 16 + c0];

    const int rsel0 = (c0 < 8) ? 0 : 2;
    const int ugl = ugrp * 32 + p2 * 8 + (c0 & 7);
    const bool lo = (c0 < 8);

    // this wave's row half: role0 -> m 0,1 ; role1 -> m 2,3
    int len4[4];
#pragma unroll
    for (int mm = 0; mm < 2; mm++)
#pragma unroll
        for (int rr = 0; rr < 2; rr++) {
            const int m_eff = role * 2 + mm;
            len4[mm * 2 + rr] = lens[r * 64 + m_eff * 16 + quad * 4 + rsel0 + rr];
        }

    float c4[4] = {0, 0, 0, 0};
    float h4[4] = {0, 0, 0, 0};

    int p = 0;
#pragma unroll 1
    for (int s = 0; s < 256; s++) {
        const int t_cur = (l & 1) ? (255 - s) : s;
        const u64* hread = hl + (s & 1) * 65536;
        u64* hwrite = hl + ((s + 1) & 1) * 65536;

        f32x4 acc[4];
#pragma unroll
        for (int m = 0; m < 4; m++) {
            f32x4 z = {0.f, 0.f, 0.f, 0.f};
            acc[m] = z;
        }
        uint2 sv[4];
        u64 hv[8];

        // ---- x chunks ----
        LOADX(0, 0); WRLDS(p); __syncthreads();
        LOADX(1, 0);
        MCHUNK(p, 0, 4);                       // chunk x0
        WRLDS(p ^ 1); __syncthreads();
        LOADX(2, 1);
        MCHUNK(p ^ 1, 4, 4);                   // chunk x1
        WRLDS(p); __syncthreads();
        if (s > 0) LOADH(0);                   // issue h reads, overlap x2 MFMA
        MCHUNK(p, 8, 2);                       // chunk x2 (K=64 valid)
        if (s > 0) {
            WRLDSH(p ^ 1, 0); __syncthreads(); // wait+verify tags + h0 into LDS
            LOADH(1);
            MCHUNK(p ^ 1, 10, 4);              // h0
            WRLDSH(p, 1); __syncthreads();
            LOADH(2);
            MCHUNK(p, 14, 4);                  // h1
            WRLDSH(p ^ 1, 2); __syncthreads();
            LOADH(3);
            MCHUNK(p ^ 1, 18, 4);              // h2
            WRLDSH(p, 3); __syncthreads();
            MCHUNK(p, 22, 4);                  // h3
        }

        // ---- epilogue: gate-pair LDS exchange, state update, tagged store ----
        {
            float zz[4][4], tv[4][4];
#pragma unroll
            for (int m = 0; m < 4; m++)
#pragma unroll
                for (int reg = 0; reg < 4; reg++)
                    zz[m][reg] = acc[m][reg] + biasw;
#pragma unroll
            for (int m = 0; m < 4; m++)
#pragma unroll
                for (int reg = 0; reg < 4; reg++)
                    tv[m][reg] = __shfl_xor(zz[m][reg], 8, 64);

            // write the FOREIGN row half's gate pair to LDS
#pragma unroll
            for (int mm = 0; mm < 2; mm++)
#pragma unroll
                for (int rr = 0; rr < 2; rr++) {
                    const int m_for = (role ? 0 : 2) + mm;   // foreign half
                    const int reg = rsel0 + rr;
                    float gA = lo ? zz[m_for][reg] : tv[m_for][reg]; // i or f
                    float gB = lo ? tv[m_for][reg] : zz[m_for][reg]; // j or o
                    if (role == 0) exch0[p2][mm][rr][L] = make_float2(gA, gB);
                    else           exch1[p2][mm][rr][L] = make_float2(gA, gB);
                }
            __syncthreads();

            // process OWN row half with the other wave's gate pair
#pragma unroll
            for (int mm = 0; mm < 2; mm++)
#pragma unroll
                for (int rr = 0; rr < 2; rr++) {
                    const int m_own = role * 2 + mm;
                    const int reg = rsel0 + rr, idx = mm * 2 + rr;
                    float gA = lo ? zz[m_own][reg] : tv[m_own][reg];
                    float gB = lo ? tv[m_own][reg] : zz[m_own][reg];
                    float iv, jv, fv, ov;
                    if (role == 0) {
                        iv = gA; jv = gB;
                        float2 e = exch1[p2][mm][rr][L];
                        fv = e.x; ov = e.y;
                    } else {
                        fv = gA; ov = gB;
                        float2 e = exch0[p2][mm][rr][L];
                        iv = e.x; jv = e.y;
                    }
                    float nc = c4[idx] * sigf(fv + 1.0f) + sigf(iv) * tanhf_(jv);
                    float nh = tanhf_(nc) * sigf(ov);
                    const bool mk = (t_cur < len4[idx]);
                    c4[idx] = mk ? nc : c4[idx];
                    h4[idx] = mk ? nh : h4[idx];
                    const int b = r * 64 + m_own * 16 + quad * 4 + reg;
                    u32 hb = (u32)f2bf(h4[idx]);
                    u32 pr = __shfl_xor(hb, 1, 64);
                    if ((c0 & 1) == 0) {
                        u64 pk = ((u64)(u32)(s + 1) << 32)
                               | (u64)(hb | (pr << 16));
                        sth_sc0(hwrite + (size_t)b * 256 + (ugl >> 1), pk);
                    }
                }
        }
        p ^= 1;    // no end-of-step barrier: tag-signaled data needs no drain
    }

    // ---- final cell states -> xcat [256][2048] = [c_pfw|c_pbw|c_hfw|c_hbw] ----
#pragma unroll
    for (int mm = 0; mm < 2; mm++)
#pragma unroll
        for (int rr = 0; rr < 2; rr++) {
            const int m_own = role * 2 + mm;
            const int reg = rsel0 + rr, idx = mm * 2 + rr;
            const int b = r * 64 + m_own * 16 + quad * 4 + reg;
            P_.xcat[(size_t)b * 2048 + l * 512 + ugl] = f2bf(c4[idx]);
        }
}

// ---------------------------------------------------------------------------
// MLP GEMM: out[M=256][N] = act(A_bf16[256][K] @ W_f32[K][N] + bias_f32).
// B-fragments gathered strided from original f32 W (cache-resident, 2 GFLOP).
// ---------------------------------------------------------------------------
__global__ __launch_bounds__(256) void birnn_mlp(const u16* __restrict__ A,
                                                 const float* __restrict__ W,
                                                 const float* __restrict__ bias,
                                                 u16* __restrict__ out,
                                                 int N, int K, int act)
{
    const int tid = threadIdx.x, wq = tid >> 6, L = tid & 63;
    const int c0 = L & 15, quad = L >> 4;
    const int bm = blockIdx.x * 64;
    const int col = blockIdx.y * 64 + wq * 16 + c0;
    f32x4 acc[4];
#pragma unroll
    for (int m = 0; m < 4; m++) { f32x4 z = {0.f, 0.f, 0.f, 0.f}; acc[m] = z; }
    const int ksn = K >> 5;
    for (int ks = 0; ks < ksn; ks++) {
        bf16x8 bfrag;
#pragma unroll
        for (int j = 0; j < 8; j++)
            bfrag[j] = (short)f2bf(W[(size_t)(ks * 32 + quad * 8 + j) * N + col]);
#pragma unroll
        for (int m = 0; m < 4; m++) {
            bf16x8 afrag = *(const bf16x8*)(A + (size_t)(bm + m * 16 + c0) * K
                                            + ks * 32 + quad * 8);
            acc[m] = __builtin_amdgcn_mfma_f32_16x16x32_bf16(afrag, bfrag, acc[m], 0, 0, 0);
        }
    }
    const float bs = bias[col];
#pragma unroll
    for (int m = 0; m < 4; m++)
#pragma unroll
        for (int reg = 0; reg < 4; reg++) {
            float v = acc[m][reg] + bs;
            if (act) v = tanhf_(v);
            out[(size_t)(bm + m * 16 + quad * 4 + reg) * N + col] = f2bf(v);
        }
}

// Final layer: logits_f32[256][3] = h3_bf16[256][1024] @ W4_f32[1024][3] + b4.
__global__ void birnn_out(const u16* __restrict__ h3, const float* __restrict__ W4,
                          const float* __restrict__ b4, float* __restrict__ out)
{
    const int b = blockIdx.x;
    const int w = threadIdx.x >> 6, lane = threadIdx.x & 63;
    float s = 0.f;
    for (int it = 0; it < 16; it++) {
        int k = it * 64 + lane;
        s += bf2f(h3[b * 1024 + k]) * W4[k * 3 + w];
    }
#pragma unroll
    for (int off = 32; off > 0; off >>= 1) s += __shfl_down(s, off, 64);
    if (lane == 0) out[b * 3 + w] = s + b4[w];
}

// ---------------------------------------------------------------------------
extern "C" void kernel_launch(void* const* d_in, const int* in_sizes, int n_in,
                              void* d_out, int out_size, void* d_ws, size_t ws_size,
                              hipStream_t stream)
{
    const float* prem = (const float*)d_in[0];
    const float* hyp  = (const float*)d_in[1];
    const int* plen = (const int*)d_in[2];
    const int* hlen = (const int*)d_in[3];
    const float* Wx[4] = {(const float*)d_in[4],  (const float*)d_in[7],
                          (const float*)d_in[10], (const float*)d_in[13]};
    const float* Wh[4] = {(const float*)d_in[5],  (const float*)d_in[8],
                          (const float*)d_in[11], (const float*)d_in[14]};
    const float* bb[4] = {(const float*)d_in[6],  (const float*)d_in[9],
                          (const float*)d_in[12], (const float*)d_in[15]};
    const float* W1 = (const float*)d_in[16]; const float* b1 = (const float*)d_in[17];
    const float* W2 = (const float*)d_in[18]; const float* b2 = (const float*)d_in[19];
    const float* W3 = (const float*)d_in[20]; const float* b3 = (const float*)d_in[21];
    const float* W4 = (const float*)d_in[22]; const float* b4 = (const float*)d_in[23];

    // workspace carve (19,955,712 B total)
    char* w = (char*)d_ws;
    u64*  hbuf = (u64*)(w + 0);            // 4 x 2 x [256][256] u64 = 4,194,304
    u16*  xcat = (u16*)(w + 4194304);      // [256][2048] bf16 = 1,048,576
    u16*  h1   = (u16*)(w + 5242880);      // [256][1024] bf16 =   524,288
    u16*  h2   = (u16*)(w + 5767168);      // [256][1024] bf16 =   524,288
    u16*  Whp  = (u16*)(w + 6291456);      // 4 x [2048][512] bf16 = 8,388,608
    u16*  Wxp  = (u16*)(w + 14680064);     // 4 x [2048][320] bf16 = 5,242,880
    float* bp  = (float*)(w + 19922944);   // 4 x 2048 f32 = 32,768
    u16*  h3   = xcat;                     // xcat dead after MLP layer 1: reuse

    if (ws_size < 19955712) return;        // too-small ws -> zero output
                                           // (finite signature, diagnosable)

    hipMemsetAsync(hbuf, 0, 4194304, stream);   // tags = 0: never matches s>=1
    hipMemsetAsync(xcat, 0, 1048576, stream);

    for (int l = 0; l < 4; l++) {
        birnn_tr<<<dim3(8, 32), 256, 0, stream>>>(Wh[l], Whp + (size_t)l * 2048 * 512,
                                                  512, 2048, 512, 1);
        birnn_tr<<<dim3(5, 32), 256, 0, stream>>>(Wx[l], Wxp + (size_t)l * 2048 * 320,
                                                  300, 2048, 320, 1);
    }
    birnn_bias<<<dim3(8, 4), 256, 0, stream>>>(bb[0], bb[1], bb[2], bb[3], bp);

    RnnP pp{prem, hyp, plen, hlen, Whp, Wxp, bp, hbuf, xcat};
    birnn_rnn<<<dim3(256), dim3(512), 0, stream>>>(pp);

    birnn_mlp<<<dim3(4, 16), 256, 0, stream>>>(xcat, W1, b1, h1, 1024, 2048, 1);
    birnn_mlp<<<dim3(4, 16), 256, 0, stream>>>(h1,   W2, b2, h2, 1024, 1024, 1);
    birnn_mlp<<<dim3(4, 16), 256, 0, stream>>>(h2,   W3, b3, h3, 1024, 1024, 1);
    birnn_out<<<dim3(256), 192, 0, stream>>>(h3, W4, b4, (float*)d_out);
}